// Round 6
// baseline (479.840 us; speedup 1.0000x reference)
//
#include <hip/hip_runtime.h>
#include <math.h>

#define NB 8
#define NN 1024
#define DD 512

typedef unsigned short u16;
typedef unsigned int u32;
typedef unsigned long long u64;
typedef __attribute__((ext_vector_type(8))) short bfrag;
typedef __attribute__((ext_vector_type(4))) float ffrag;

__device__ __forceinline__ u16 f2b(float f) {
    union { float f; u32 u; } v; v.f = f;
    u32 r = v.u + 0x7fffu + ((v.u >> 16) & 1u);   // RNE
    return (u16)(r >> 16);
}
__device__ __forceinline__ float b2f(u16 b) {
    union { u32 u; float f; } v; v.u = ((u32)b) << 16;
    return v.f;
}

// A&S 7.1.26 erf: |err| <= 1.5e-7
__device__ __forceinline__ float gelu_cheap(float v) {
    float s = v * 0.70710678118654752f;
    float a = fabsf(s);
    float t = 1.0f / (1.0f + 0.3275911f * a);
    float p = ((((1.061405429f * t - 1.453152027f) * t + 1.421413741f) * t
                - 0.284496736f) * t + 0.254829592f) * t;
    float erfa = 1.0f - p * __expf(-a * a);
    float erfs = copysignf(erfa, s);
    return 0.5f * v * (1.0f + erfs);
}

// async global->LDS, 16B per lane; lds base must be wave-uniform
__device__ __forceinline__ void gload_lds16(const void* g, void* l) {
    __builtin_amdgcn_global_load_lds(
        (const __attribute__((address_space(1))) void*)g,
        (__attribute__((address_space(3))) void*)l, 16, 0, 0);
}

// ---------------- mask pack: adj + diag -> bitmask [B*N][16] u64 -----------------
__global__ __launch_bounds__(256) void mask_pack(const int* __restrict__ adj,
                                                 u64* __restrict__ mb) {
    int idx = blockIdx.x * 256 + threadIdx.x;     // < 8*1024*16
    int w = idx & 15;
    int bi = idx >> 4;
    int i = bi & 1023;
    const int4* p = (const int4*)(adj + (size_t)bi * NN + w * 64);
    u64 m = 0;
#pragma unroll
    for (int q = 0; q < 16; ++q) {
        int4 v = p[q];
        if (v.x > 0) m |= 1ull << (q * 4 + 0);
        if (v.y > 0) m |= 1ull << (q * 4 + 1);
        if (v.z > 0) m |= 1ull << (q * 4 + 2);
        if (v.w > 0) m |= 1ull << (q * 4 + 3);
    }
    if (w == (i >> 6)) m |= 1ull << (i & 63);
    mb[idx] = m;
}

// ---------------- transpose + cvt: in fp32 [R][C] -> out bf16 [C][R] -------------
__global__ __launch_bounds__(256) void transpose_cvt(
    const float* __restrict__ in, u16* __restrict__ out,
    int R, int C, size_t inStr, size_t outStr)
{
    __shared__ float tile[32][33];
    int z = blockIdx.z;
    int r0 = blockIdx.y * 32, c0 = blockIdx.x * 32;
    int t = threadIdx.x;
    int tr = t >> 3, tc = (t & 7) * 4;
    float4 v = *(const float4*)(in + inStr * z + (size_t)(r0 + tr) * C + c0 + tc);
    tile[tr][tc + 0] = v.x; tile[tr][tc + 1] = v.y;
    tile[tr][tc + 2] = v.z; tile[tr][tc + 3] = v.w;
    __syncthreads();
    u32 w0 = (u32)f2b(tile[tc + 0][tr]) | ((u32)f2b(tile[tc + 1][tr]) << 16);
    u32 w1 = (u32)f2b(tile[tc + 2][tr]) | ((u32)f2b(tile[tc + 3][tr]) << 16);
    uint2 wv; wv.x = w0; wv.y = w1;
    *(uint2*)(out + outStr * z + (size_t)(c0 + tr) * R + r0 + tc) = wv;
}

// ---------------- score projection (layer 0 only) --------------------------------
__global__ __launch_bounds__(256) void score_proj_kernel(
    const float* __restrict__ x, const float* __restrict__ w,
    float* __restrict__ si, float* __restrict__ sj)
{
    int wave = threadIdx.x >> 6;
    int lane = threadIdx.x & 63;
    int row = blockIdx.x * 4 + wave;
    const float4* xr = (const float4*)(x + (size_t)row * DD) + lane * 2;
    const float4* w1 = (const float4*)(w) + lane * 2;
    const float4* w2 = (const float4*)(w + DD) + lane * 2;
    float a = 0.f, b2 = 0.f;
#pragma unroll
    for (int c = 0; c < 2; ++c) {
        float4 xv = xr[c], wa = w1[c], wb = w2[c];
        a  += xv.x * wa.x + xv.y * wa.y + xv.z * wa.z + xv.w * wa.w;
        b2 += xv.x * wb.x + xv.y * wb.y + xv.z * wb.z + xv.w * wb.w;
    }
#pragma unroll
    for (int off = 32; off > 0; off >>= 1) {
        a  += __shfl_xor(a, off);
        b2 += __shfl_xor(b2, off);
    }
    if (lane == 0) { si[row] = a; sj[row] = b2; }
}

// ---------------- softmax -> P (bf16), register-resident -------------------------
__global__ __launch_bounds__(256) void softmax_p(
    const float* __restrict__ si, const float* __restrict__ sj,
    const float* __restrict__ attn_b, const u64* __restrict__ mb,
    u16* __restrict__ P)
{
    __shared__ u16 sb[8 * NN];        // 16 KB
    int b  = blockIdx.x >> 7;
    int i0 = (blockIdx.x & 127) * 8;
    int tid = threadIdx.x;
    int r = tid >> 5, l32 = tid & 31;
    int i = i0 + r;
    float bb = attn_b[0];
    float siv = si[b * NN + i];
    const float* sjb = sj + b * NN;
    const u64* mbr = mb + ((size_t)b * NN + i) * 16;

    float sv[32];
    float mx = -INFINITY;
#pragma unroll
    for (int q = 0; q < 32; ++q) {
        int j = q * 32 + l32;
        u64 w = mbr[q >> 1];
        int bit = ((q & 1) << 5) + l32;
        float s = siv + sjb[j] + bb;
        s = (s >= 0.f) ? s : 0.2f * s;
        s = ((w >> bit) & 1ull) ? s : -INFINITY;
        sv[q] = s;
        mx = fmaxf(mx, s);
    }
#pragma unroll
    for (int off = 16; off > 0; off >>= 1) mx = fmaxf(mx, __shfl_xor(mx, off, 32));
    float sum = 0.f;
#pragma unroll
    for (int q = 0; q < 32; ++q) {
        float p = __expf(sv[q] - mx);
        sv[q] = p;
        sum += p;
    }
#pragma unroll
    for (int off = 16; off > 0; off >>= 1) sum += __shfl_xor(sum, off, 32);
    float inv = 1.f / sum;
#pragma unroll
    for (int q = 0; q < 32; ++q)
        sb[r * NN + q * 32 + l32] = f2b(sv[q] * inv);
    __syncthreads();
    const uint4* src = (const uint4*)sb;
    uint4* dst = (uint4*)(P + ((size_t)b * NN + i0) * NN);
#pragma unroll
    for (int t = 0; t < 4; ++t) dst[t * 256 + tid] = src[t * 256 + tid];
}

// ======================= bf16 MFMA GEMM: 64x128 tile, BK=64, LDS double-buffer ===
// EPI: 0 = +res(fp32), fp32 out | 1 = +bias, gelu, bf16 out | 2 = +bias +res(bf16), fp32 out
template <int EPI>
__global__ __launch_bounds__(256) void gemm64(
    const u16* __restrict__ A, const u16* __restrict__ Bm,
    const float* __restrict__ bias, const void* __restrict__ res,
    void* __restrict__ Cout, int K, int N, int lda, int ldb,
    size_t aStr, size_t bStr, size_t cStr, size_t resStr)
{
    // u16 elems: A buf0 [0,4096) buf1 [4096,8192); B buf0 [8192,16384) buf1 [16384,24576)
    __shared__ __align__(16) u16 lds[24576];   // 48 KB
    int z = blockIdx.z;
    int m0 = blockIdx.y * 64, n0 = blockIdx.x * 128;
    int tid = threadIdx.x;
    int lane = tid & 63, wv = tid >> 6;

    const u16* ag[2]; const u16* bg[4];
    u32 la[2], lb[4];
#pragma unroll
    for (int i = 0; i < 2; ++i) {
        int q = i * 256 + tid;
        int row = q >> 3, c = q & 7;
        ag[i] = A + aStr * z + (size_t)(m0 + row) * lda + (c ^ (row & 7)) * 8;
        la[i] = i * 2048 + wv * 512;
    }
#pragma unroll
    for (int i = 0; i < 4; ++i) {
        int q = i * 256 + tid;
        int row = q >> 3, c = q & 7;
        bg[i] = Bm + bStr * z + (size_t)(n0 + row) * ldb + (c ^ (row & 7)) * 8;
        lb[i] = 8192 + i * 2048 + wv * 512;
    }

    int mw = (wv >> 1) * 32, nw = (wv & 1) * 64;
    int lr = lane & 15, lq = lane >> 4;
    int sw = lr & 7;

    ffrag acc[2][4];
#pragma unroll
    for (int i = 0; i < 2; ++i)
#pragma unroll
        for (int j = 0; j < 4; ++j) acc[i][j] = (ffrag){0.f, 0.f, 0.f, 0.f};

    // prologue: stage k=0 into buf0
#pragma unroll
    for (int i = 0; i < 2; ++i) gload_lds16(ag[i], &lds[la[i]]);
#pragma unroll
    for (int i = 0; i < 4; ++i) gload_lds16(bg[i], &lds[lb[i]]);

    for (int k0 = 0; k0 < K; k0 += 64) {
        int cur = (k0 >> 6) & 1;
        if (k0 + 64 < K) {
#pragma unroll
            for (int i = 0; i < 2; ++i)
                gload_lds16(ag[i] + k0 + 64, &lds[((cur ^ 1) << 12) + la[i]]);
#pragma unroll
            for (int i = 0; i < 4; ++i)
                gload_lds16(bg[i] + k0 + 64, &lds[((cur ^ 1) << 13) + lb[i]]);
            asm volatile("s_waitcnt vmcnt(6)" ::: "memory");
        } else {
            asm volatile("s_waitcnt vmcnt(0)" ::: "memory");
        }
        asm volatile("s_barrier" ::: "memory");

        const u16* Ab = &lds[cur << 12];
        const u16* Bb = &lds[8192 + (cur << 13)];
#pragma unroll
        for (int h = 0; h < 2; ++h) {
            bfrag af[2], bf[4];
#pragma unroll
            for (int i = 0; i < 2; ++i)
                af[i] = *(const bfrag*)&Ab[(mw + i * 16 + lr) * 64 + ((h * 4 + lq) ^ sw) * 8];
#pragma unroll
            for (int j = 0; j < 4; ++j)
                bf[j] = *(const bfrag*)&Bb[(nw + j * 16 + lr) * 64 + ((h * 4 + lq) ^ sw) * 8];
#pragma unroll
            for (int i = 0; i < 2; ++i)
#pragma unroll
                for (int j = 0; j < 4; ++j)
                    acc[i][j] = __builtin_amdgcn_mfma_f32_16x16x32_bf16(af[i], bf[j], acc[i][j], 0, 0, 0);
        }
        asm volatile("s_waitcnt lgkmcnt(0)\ns_barrier" ::: "memory");
    }

    float* Cf = (float*)Cout + cStr * z;
    u16*   Cb = (u16*)Cout + cStr * z;
    const float* resf = (const float*)res;
    const u16*   resb = (const u16*)res;
#pragma unroll
    for (int i = 0; i < 2; ++i) {
        int row = m0 + mw + i * 16 + lq * 4;
#pragma unroll
        for (int j = 0; j < 4; ++j) {
            int col = n0 + nw + j * 16 + lr;
            float bv = (EPI != 0) ? bias[col] : 0.f;
#pragma unroll
            for (int r = 0; r < 4; ++r) {
                float v = acc[i][j][r] + bv;
                size_t off = (size_t)(row + r) * N + col;
                if (EPI == 1) {
                    Cb[off] = f2b(gelu_cheap(v));
                } else if (EPI == 0) {
                    Cf[off] = v + resf[resStr * z + off];
                } else {
                    Cf[off] = v + b2f(resb[off]);
                }
            }
        }
    }
}

// ======================= bf16 MFMA GEMM: 128x128 tile, BK=64, dbuf (FFN1) ========
template <int EPI>
__global__ __launch_bounds__(256) void gemm128p(
    const u16* __restrict__ A, const u16* __restrict__ Bm,
    const float* __restrict__ bias, const void* __restrict__ res,
    void* __restrict__ Cout, int K, int N, int lda, int ldb,
    size_t aStr, size_t bStr, size_t cStr, size_t resStr)
{
    // u16 elems: A buf0 [0,8192) buf1 [8192,16384); B buf0 [16384,24576) buf1 [24576,32768)
    __shared__ __align__(16) u16 lds[32768];   // 64 KB
    int z = blockIdx.z;
    int m0 = blockIdx.y * 128, n0 = blockIdx.x * 128;
    int tid = threadIdx.x;
    int lane = tid & 63, wv = tid >> 6;

    const u16* ag[4]; const u16* bg[4];
    u32 la[4], lb[4];
#pragma unroll
    for (int i = 0; i < 4; ++i) {
        int q = i * 256 + tid;
        int row = q >> 3, c = q & 7;
        int gc = c ^ (row & 7);
        ag[i] = A  + aStr * z + (size_t)(m0 + row) * lda + gc * 8;
        bg[i] = Bm + bStr * z + (size_t)(n0 + row) * ldb + gc * 8;
        la[i] = i * 2048 + wv * 512;
        lb[i] = 16384 + i * 2048 + wv * 512;
    }

    int mw = (wv >> 1) * 64, nw = (wv & 1) * 64;
    int lr = lane & 15, lq = lane >> 4;
    int sw = lr & 7;

    ffrag acc[4][4];
#pragma unroll
    for (int i = 0; i < 4; ++i)
#pragma unroll
        for (int j = 0; j < 4; ++j) acc[i][j] = (ffrag){0.f, 0.f, 0.f, 0.f};

    // prologue: stage k=0 into buf0
#pragma unroll
    for (int i = 0; i < 4; ++i) gload_lds16(ag[i], &lds[la[i]]);
#pragma unroll
    for (int i = 0; i < 4; ++i) gload_lds16(bg[i], &lds[lb[i]]);

    for (int k0 = 0; k0 < K; k0 += 64) {
        int cur = (k0 >> 6) & 1;
        if (k0 + 64 < K) {
#pragma unroll
            for (int i = 0; i < 4; ++i)
                gload_lds16(ag[i] + k0 + 64, &lds[((cur ^ 1) << 13) + la[i]]);
#pragma unroll
            for (int i = 0; i < 4; ++i)
                gload_lds16(bg[i] + k0 + 64, &lds[((cur ^ 1) << 13) + lb[i]]);
            asm volatile("s_waitcnt vmcnt(8)" ::: "memory");
        } else {
            asm volatile("s_waitcnt vmcnt(0)" ::: "memory");
        }
        asm volatile("s_barrier" ::: "memory");

        const u16* Ab = &lds[cur << 13];
        const u16* Bb = &lds[16384 + (cur << 13)];
#pragma unroll
        for (int h = 0; h < 2; ++h) {
            bfrag af[4], bf[4];
#pragma unroll
            for (int i = 0; i < 4; ++i)
                af[i] = *(const bfrag*)&Ab[(mw + i * 16 + lr) * 64 + ((h * 4 + lq) ^ sw) * 8];
#pragma unroll
            for (int j = 0; j < 4; ++j)
                bf[j] = *(const bfrag*)&Bb[(nw + j * 16 + lr) * 64 + ((h * 4 + lq) ^ sw) * 8];
#pragma unroll
            for (int i = 0; i < 4; ++i)
#pragma unroll
                for (int j = 0; j < 4; ++j)
                    acc[i][j] = __builtin_amdgcn_mfma_f32_16x16x32_bf16(af[i], bf[j], acc[i][j], 0, 0, 0);
        }
        asm volatile("s_waitcnt lgkmcnt(0)\ns_barrier" ::: "memory");
    }

    float* Cf = (float*)Cout + cStr * z;
    u16*   Cb = (u16*)Cout + cStr * z;
    const float* resf = (const float*)res;
    const u16*   resb = (const u16*)res;
#pragma unroll
    for (int i = 0; i < 4; ++i) {
        int row = m0 + mw + i * 16 + lq * 4;
#pragma unroll
        for (int j = 0; j < 4; ++j) {
            int col = n0 + nw + j * 16 + lr;
            float bv = (EPI != 0) ? bias[col] : 0.f;
#pragma unroll
            for (int r = 0; r < 4; ++r) {
                float v = acc[i][j][r] + bv;
                size_t off = (size_t)(row + r) * N + col;
                if (EPI == 1) {
                    Cb[off] = f2b(gelu_cheap(v));
                } else if (EPI == 0) {
                    Cf[off] = v + resf[resStr * z + off];
                } else {
                    Cf[off] = v + b2f(resb[off]);
                }
            }
        }
    }
}

// ---------------- layernorm over D=512, one row per block ------------------------
// BF=true: write bf16, else fp32
template <bool BF>
__global__ __launch_bounds__(256) void ln_kernel(
    const float* __restrict__ in, const float* __restrict__ g,
    const float* __restrict__ be, void* __restrict__ out)
{
    int row = blockIdx.x;
    int tid = threadIdx.x;
    const float2* rp = (const float2*)(in + (size_t)row * DD);
    float2 v = rp[tid];
    float s  = v.x + v.y;
    float ss = v.x * v.x + v.y * v.y;
#pragma unroll
    for (int off = 32; off > 0; off >>= 1) {
        s  += __shfl_xor(s, off);
        ss += __shfl_xor(ss, off);
    }
    __shared__ float sh[8];
    int wave = tid >> 6, lane = tid & 63;
    if (lane == 0) { sh[wave] = s; sh[4 + wave] = ss; }
    __syncthreads();
    float S  = sh[0] + sh[1] + sh[2] + sh[3];
    float SS = sh[4] + sh[5] + sh[6] + sh[7];
    float mean = S * (1.f / DD);
    float var  = SS * (1.f / DD) - mean * mean;
    var = fmaxf(var, 0.f);
    float rs = rsqrtf(var + 1e-5f);
    float2 gv = ((const float2*)g)[tid];
    float2 bv = ((const float2*)be)[tid];
    float ox = (v.x - mean) * rs * gv.x + bv.x;
    float oy = (v.y - mean) * rs * gv.y + bv.y;
    if (BF) {
        u32 w = (u32)f2b(ox) | ((u32)f2b(oy) << 16);
        ((u32*)out)[(size_t)row * (DD / 2) + tid] = w;
    } else {
        float2 o; o.x = ox; o.y = oy;
        ((float2*)out)[(size_t)row * (DD / 2) + tid] = o;
    }
}

// ---------------- ln2 + next-layer score projection fused ------------------------
// writes fp32 x (in-place ok: block touches only its row) + si/sj for next layer
__global__ __launch_bounds__(256) void ln2_score(
    const float* __restrict__ in, const float* __restrict__ g,
    const float* __restrict__ be, const float* __restrict__ wnx,
    float* __restrict__ xout, float* __restrict__ si, float* __restrict__ sj)
{
    int row = blockIdx.x;
    int tid = threadIdx.x;
    const float2* rp = (const float2*)(in + (size_t)row * DD);
    float2 v = rp[tid];
    float s  = v.x + v.y;
    float ss = v.x * v.x + v.y * v.y;
#pragma unroll
    for (int off = 32; off > 0; off >>= 1) {
        s  += __shfl_xor(s, off);
        ss += __shfl_xor(ss, off);
    }
    __shared__ float sh[16];
    int wave = tid >> 6, lane = tid & 63;
    if (lane == 0) { sh[wave] = s; sh[4 + wave] = ss; }
    __syncthreads();
    float S  = sh[0] + sh[1] + sh[2] + sh[3];
    float SS = sh[4] + sh[5] + sh[6] + sh[7];
    float mean = S * (1.f / DD);
    float var  = SS * (1.f / DD) - mean * mean;
    var = fmaxf(var, 0.f);
    float rs = rsqrtf(var + 1e-5f);
    float2 gv = ((const float2*)g)[tid];
    float2 bv = ((const float2*)be)[tid];
    float ox = (v.x - mean) * rs * gv.x + bv.x;
    float oy = (v.y - mean) * rs * gv.y + bv.y;
    float2 o; o.x = ox; o.y = oy;
    ((float2*)xout)[(size_t)row * (DD / 2) + tid] = o;

    float2 wa = ((const float2*)wnx)[tid];
    float2 wb = ((const float2*)(wnx + DD))[tid];
    float a = ox * wa.x + oy * wa.y;
    float b = ox * wb.x + oy * wb.y;
#pragma unroll
    for (int off = 32; off > 0; off >>= 1) {
        a += __shfl_xor(a, off);
        b += __shfl_xor(b, off);
    }
    if (lane == 0) { sh[8 + wave] = a; sh[12 + wave] = b; }
    __syncthreads();
    if (tid == 0) {
        si[row] = sh[8] + sh[9] + sh[10] + sh[11];
        sj[row] = sh[12] + sh[13] + sh[14] + sh[15];
    }
}

extern "C" void kernel_launch(void* const* d_in, const int* in_sizes, int n_in,
                              void* d_out, int out_size, void* d_ws, size_t ws_size,
                              hipStream_t stream) {
    const float* nf     = (const float*)d_in[0];
    const int*   adj    = (const int*)d_in[1];
    const float* attn_w = (const float*)d_in[2];
    const float* attn_b = (const float*)d_in[3];
    const float* W1     = (const float*)d_in[4];
    const float* b1     = (const float*)d_in[5];
    const float* W2     = (const float*)d_in[6];
    const float* b2     = (const float*)d_in[7];
    const float* g1     = (const float*)d_in[8];
    const float* be1    = (const float*)d_in[9];
    const float* g2     = (const float*)d_in[10];
    const float* be2    = (const float*)d_in[11];
    float* out = (float*)d_out;

    char* wsb = (char*)d_ws;
    float* x_cur = (float*)(wsb);                      // 16 MB [0,16M)
    u16*   h_bf  = (u16*)(wsb + 16777216);             //  8 MB [16,24M)
    char*  scr   = wsb + 25165824;                     // 32 MB [24,56M)
    u16*   P     = (u16*)scr;                          //   [24,40M)
    float* hres  = (float*)(scr + 16777216);           //   [40,56M)
    u16*   mid   = (u16*)scr;                          //   [24,56M) after ln1 (P,hres dead)
    u16*   xT    = (u16*)(wsb + 58720256);             //  8 MB [56,64M)
    u16*   W1t   = (u16*)(wsb + 67108864);             //  6 MB [64,70M)
    u16*   W2t   = (u16*)(wsb + 73400320);             //  6 MB [70,76M)
    u64*   mask  = (u64*)(wsb + 79691776);             //  1 MB [76,77M)
    float* si    = (float*)(wsb + 80740352);           // 32 KB
    float* sj    = (float*)(wsb + 80773120);           // 32 KB

    // prep (re-done every call; cheap)
    mask_pack<<<512, 256, 0, stream>>>(adj, mask);
    transpose_cvt<<<dim3(64, 16, 3), 256, 0, stream>>>(W1, W1t, 512, 2048,
                                                       (size_t)512 * 2048, (size_t)512 * 2048);
    transpose_cvt<<<dim3(16, 64, 3), 256, 0, stream>>>(W2, W2t, 2048, 512,
                                                       (size_t)2048 * 512, (size_t)2048 * 512);

    for (int l = 0; l < 3; ++l) {
        const float* xin = (l == 0) ? nf : x_cur;
        if (l == 0)
            score_proj_kernel<<<2048, 256, 0, stream>>>(xin, attn_w, si, sj);
        transpose_cvt<<<dim3(16, 32, 8), 256, 0, stream>>>(xin, xT, 1024, 512,
                                                           (size_t)NN * DD, (size_t)NN * DD);
        softmax_p<<<1024, 256, 0, stream>>>(si, sj, attn_b + l, mask, P);
        // agg: hres[b] = P[b] @ x[b]^T + x[b]   (64x128 tiles, 512 blocks, K=1024)
        gemm64<0><<<dim3(4, 16, 8), 256, 0, stream>>>(
            P, xT, nullptr, xin, hres, 1024, 512, 1024, 1024,
            (size_t)NN * NN, (size_t)DD * NN, (size_t)NN * DD, (size_t)NN * DD);
        // ln1 -> bf16 h
        ln_kernel<true><<<8192, 256, 0, stream>>>(hres, g1 + (size_t)l * 512, be1 + (size_t)l * 512, h_bf);
        // FFN1: mid = gelu(h @ W1 + b1)  (bf16 out; 128x128 tiles, 1024 blocks, K=512)
        gemm128p<1><<<dim3(16, 64, 1), 256, 0, stream>>>(
            h_bf, W1t + (size_t)l * 1048576, b1 + (size_t)l * 2048, nullptr, mid,
            512, 2048, 512, 512, 0, 0, 0, 0);
        // FFN2: x_cur = mid @ W2 + b2 + h   (64x128 tiles, 512 blocks, K=2048)
        gemm64<2><<<dim3(4, 128, 1), 256, 0, stream>>>(
            mid, W2t + (size_t)l * 1048576, b2 + (size_t)l * 512, h_bf, x_cur,
            2048, 512, 2048, 2048, 0, 0, 0, 0);
        if (l == 2) {
            ln_kernel<false><<<8192, 256, 0, stream>>>(x_cur, g2 + (size_t)l * 512,
                                                       be2 + (size_t)l * 512, out);
        } else {
            // ln2 + next layer's score projection fused (in-place on x_cur)
            ln2_score<<<8192, 256, 0, stream>>>(x_cur, g2 + (size_t)l * 512,
                                                be2 + (size_t)l * 512,
                                                attn_w + (size_t)(l + 1) * 1024,
                                                x_cur, si, sj);
        }
    }
}